// Round 5
// baseline (744.862 us; speedup 1.0000x reference)
//
#include <hip/hip_runtime.h>
#include <stdint.h>

typedef __attribute__((ext_vector_type(8))) short bf16x8;
typedef __attribute__((ext_vector_type(4))) float f32x4;

#define MFMA16(a, b, c) __builtin_amdgcn_mfma_f32_16x16x32_bf16((a), (b), (c), 0, 0, 0)

static constexpr int BATCH = 4;
static constexpr int QLEN  = 4096;
static constexpr int KLEN  = 4096;
static constexpr int DDIM  = 64;
static constexpr int VDIM  = 64;
static constexpr float SCALE = 0.125f;   // 1/sqrt(64)

__device__ __forceinline__ short f2bf(float x) {
    union { float f; uint32_t u; } v; v.f = x;
    uint32_t u = v.u;
    return (short)((u + 0x7fffu + ((u >> 16) & 1u)) >> 16);   // RNE
}

__device__ __forceinline__ bf16x8 neg8(bf16x8 x) {
#pragma unroll
    for (int i = 0; i < 8; ++i) x[i] ^= (short)0x8000;
    return x;
}

// Load 8 CONSECUTIVE complex elements starting at element index eidx.
// isbf: packed bf16 pairs (one u32 per element). else: float2 per element.
__device__ __forceinline__ void load8(const void* base, size_t eidx, bool isbf,
                                      bf16x8& re, bf16x8& im) {
    if (isbf) {
        const uint32_t* p = (const uint32_t*)base + eidx;
        uint4 a = ((const uint4*)p)[0];
        uint4 b = ((const uint4*)p)[1];
        uint32_t x[8] = {a.x, a.y, a.z, a.w, b.x, b.y, b.z, b.w};
#pragma unroll
        for (int j = 0; j < 8; ++j) {
            re[j] = (short)(x[j] & 0xffffu);
            im[j] = (short)(x[j] >> 16);
        }
    } else {
        const float4* p = (const float4*)((const float*)base + 2 * eidx);
        float4 f0 = p[0], f1 = p[1], f2 = p[2], f3 = p[3];
        re[0] = f2bf(f0.x); im[0] = f2bf(f0.y); re[1] = f2bf(f0.z); im[1] = f2bf(f0.w);
        re[2] = f2bf(f1.x); im[2] = f2bf(f1.y); re[3] = f2bf(f1.z); im[3] = f2bf(f1.w);
        re[4] = f2bf(f2.x); im[4] = f2bf(f2.y); re[5] = f2bf(f2.z); im[5] = f2bf(f2.w);
        re[6] = f2bf(f3.x); im[6] = f2bf(f3.y); re[7] = f2bf(f3.z); im[7] = f2bf(f3.w);
    }
}

// Gather 8 complex elements at element indices ebase + j*VDIM (a column of V).
__device__ __forceinline__ void load8_strided(const void* base, size_t ebase, bool isbf,
                                              bf16x8& re, bf16x8& im) {
    if (isbf) {
        const uint32_t* p = (const uint32_t*)base;
#pragma unroll
        for (int j = 0; j < 8; ++j) {
            uint32_t x = p[ebase + (size_t)j * VDIM];
            re[j] = (short)(x & 0xffffu);
            im[j] = (short)(x >> 16);
        }
    } else {
        const float2* p = (const float2*)base;
#pragma unroll
        for (int j = 0; j < 8; ++j) {
            float2 f = p[ebase + (size_t)j * VDIM];
            re[j] = f2bf(f.x);
            im[j] = f2bf(f.y);
        }
    }
}

// ---------- self-contained flash-style complex attention, one wave per 16 q-rows ----------
__launch_bounds__(64)
__global__ void cattn_kernel(const void* __restrict__ Qp, const void* __restrict__ Kp,
                             const void* __restrict__ Vp, float2* __restrict__ out) {
    __shared__ __align__(16) uint16_t sPr[16][40];   // stride 40 elems = 80 B (16B-aligned rows)
    __shared__ __align__(16) uint16_t sPi[16][40];

    const int lane = threadIdx.x;
    const int r    = lane & 15;
    const int quad = lane >> 4;
    const int b    = blockIdx.y;
    const int q0   = blockIdx.x * 16;

    // ---- in-kernel dtype detect (wave-uniform, every block computes identically) ----
    const uint32_t* qu = (const uint32_t*)Qp;
    int cnt = 0;
#pragma unroll
    for (int i = 0; i < 16; ++i) {
        uint32_t e = (qu[lane * 16 + i] >> 7) & 0xFFu;
        cnt += (e >= 110u && e <= 135u) ? 1 : 0;
    }
#pragma unroll
    for (int off = 32; off > 0; off >>= 1) cnt += __shfl_xor(cnt, off);
    const bool isbf = cnt > 512;   // of 1024 samples

    // ---- Q fragments: A[m=lane&15][k=quad*8+j], two d-halves ----
    bf16x8 aQr0, aQr1, aQi0, aQi1;
    const size_t qrow = ((size_t)b * QLEN + q0 + r) * DDIM;
    load8(Qp, qrow + quad * 8, isbf, aQr0, aQi0);
    load8(Qp, qrow + 32 + quad * 8, isbf, aQr1, aQi1);
    const bf16x8 aQn0 = neg8(aQi0);
    const bf16x8 aQn1 = neg8(aQi1);

    f32x4 Yr[4], Yi[4];
#pragma unroll
    for (int i = 0; i < 4; ++i) { Yr[i] = (f32x4){0.f,0.f,0.f,0.f}; Yi[i] = (f32x4){0.f,0.f,0.f,0.f}; }
    float m_run[4] = {0.f, 0.f, 0.f, 0.f};   // norm >= 0, so 0 is a safe -inf
    float l_run[4] = {0.f, 0.f, 0.f, 0.f};

    const size_t kbase = (size_t)b * KLEN * DDIM;   // element index of K[b][0][0]
    const size_t vbase = (size_t)b * KLEN * VDIM;   // element index of V[b][0][0]

    for (int kt = 0; kt < KLEN; kt += 32) {
        // ---- S = (Q K^T) * scale, two 16-key subtiles ----
        f32x4 Sr[2], Si[2];
#pragma unroll
        for (int sub = 0; sub < 2; ++sub) {
            size_t krow = kbase + (size_t)(kt + sub * 16 + r) * DDIM;
            bf16x8 kr0, ki0, kr1, ki1;
            load8(Kp, krow + quad * 8, isbf, kr0, ki0);
            load8(Kp, krow + 32 + quad * 8, isbf, kr1, ki1);
            f32x4 c = (f32x4){0.f,0.f,0.f,0.f};
            c = MFMA16(aQr0, kr0, c);
            c = MFMA16(aQr1, kr1, c);
            c = MFMA16(aQi0, ki0, c);
            c = MFMA16(aQi1, ki1, c);
            Sr[sub] = c;
            f32x4 d = (f32x4){0.f,0.f,0.f,0.f};
            d = MFMA16(aQr0, ki0, d);
            d = MFMA16(aQr1, ki1, d);
            d = MFMA16(aQn0, kr0, d);   // -Qi * Kr
            d = MFMA16(aQn1, kr1, d);
            Si[sub] = d;
        }

        // ---- norms + row max (row = q = quad*4+g; keys vary across lanes 0..15) ----
        float nrm[2][4], tmax[4];
#pragma unroll
        for (int g = 0; g < 4; ++g) {
            float sr0 = Sr[0][g] * SCALE, si0 = Si[0][g] * SCALE;
            float sr1 = Sr[1][g] * SCALE, si1 = Si[1][g] * SCALE;
            Sr[0][g] = sr0; Si[0][g] = si0; Sr[1][g] = sr1; Si[1][g] = si1;
            nrm[0][g] = sqrtf(sr0 * sr0 + si0 * si0);
            nrm[1][g] = sqrtf(sr1 * sr1 + si1 * si1);
            tmax[g] = fmaxf(nrm[0][g], nrm[1][g]);
        }
#pragma unroll
        for (int off = 1; off < 16; off <<= 1) {
#pragma unroll
            for (int g = 0; g < 4; ++g)
                tmax[g] = fmaxf(tmax[g], __shfl_xor(tmax[g], off));
        }

        // ---- online softmax update; P = S * exp(nrm-m)/(nrm+eps) -> LDS (bf16) ----
        float alpha[4], psum[4];
#pragma unroll
        for (int g = 0; g < 4; ++g) {
            float mn = fmaxf(m_run[g], tmax[g]);
            alpha[g] = __expf(fminf(m_run[g] - mn, 0.f));
            m_run[g] = mn;
            float p0 = __expf(fminf(nrm[0][g] - mn, 0.f));
            float p1 = __expf(fminf(nrm[1][g] - mn, 0.f));
            psum[g] = p0 + p1;
            float w0 = p0 / (nrm[0][g] + 1e-9f);
            float w1 = p1 / (nrm[1][g] + 1e-9f);
            int row = quad * 4 + g;
            sPr[row][r]      = (uint16_t)f2bf(fmaxf(-2.f, fminf(2.f, Sr[0][g] * w0)));
            sPi[row][r]      = (uint16_t)f2bf(fmaxf(-2.f, fminf(2.f, Si[0][g] * w0)));
            sPr[row][r + 16] = (uint16_t)f2bf(fmaxf(-2.f, fminf(2.f, Sr[1][g] * w1)));
            sPi[row][r + 16] = (uint16_t)f2bf(fmaxf(-2.f, fminf(2.f, Si[1][g] * w1)));
        }
#pragma unroll
        for (int off = 1; off < 16; off <<= 1) {
#pragma unroll
            for (int g = 0; g < 4; ++g)
                psum[g] += __shfl_xor(psum[g], off);
        }
#pragma unroll
        for (int g = 0; g < 4; ++g) {
            l_run[g] = l_run[g] * alpha[g] + psum[g];
#pragma unroll
            for (int vs = 0; vs < 4; ++vs) { Yr[vs][g] *= alpha[g]; Yi[vs][g] *= alpha[g]; }
        }

        __syncthreads();
        // ---- P as A-fragment; V^T B-fragments gathered straight from global ----
        bf16x8 aPr = *(const bf16x8*)&sPr[r][quad * 8];
        bf16x8 aPi = *(const bf16x8*)&sPi[r][quad * 8];
        bf16x8 aPn = neg8(aPi);
#pragma unroll
        for (int vs = 0; vs < 4; ++vs) {
            // B-frag: V^T[n=vs*16+r][k=kt+quad*8+j] = V[kt+quad*8+j][vs*16+r]
            size_t ebase = vbase + (size_t)(kt + quad * 8) * VDIM + vs * 16 + r;
            bf16x8 bvr, bvi;
            load8_strided(Vp, ebase, isbf, bvr, bvi);
            Yr[vs] = MFMA16(aPr, bvr, Yr[vs]);
            Yr[vs] = MFMA16(aPn, bvi, Yr[vs]);   // - Ai*Vi
            Yi[vs] = MFMA16(aPr, bvi, Yi[vs]);
            Yi[vs] = MFMA16(aPi, bvr, Yi[vs]);
        }
        __syncthreads();
    }

    // ---- epilogue: normalize by l (>=1 structurally), store FLOAT32 complex pairs ----
#pragma unroll
    for (int g = 0; g < 4; ++g) {
        float inv = 1.0f / l_run[g];
        int q = q0 + quad * 4 + g;
#pragma unroll
        for (int vs = 0; vs < 4; ++vs) {
            int v = vs * 16 + r;
            out[((size_t)b * QLEN + q) * VDIM + v] = make_float2(Yr[vs][g] * inv, Yi[vs][g] * inv);
        }
    }
}

extern "C" void kernel_launch(void* const* d_in, const int* in_sizes, int n_in,
                              void* d_out, int out_size, void* d_ws, size_t ws_size,
                              hipStream_t stream) {
    (void)in_sizes; (void)n_in; (void)out_size; (void)d_ws; (void)ws_size;
    cattn_kernel<<<dim3(QLEN / 16, BATCH), dim3(64), 0, stream>>>(
        d_in[0], d_in[1], d_in[2], (float2*)d_out);
}

// Round 6
// 365.321 us; speedup vs baseline: 2.0389x; 2.0389x over previous
//
#include <hip/hip_runtime.h>
#include <stdint.h>

typedef __attribute__((ext_vector_type(8))) short bf16x8;
typedef __attribute__((ext_vector_type(4))) float f32x4;

#define MFMA16(a, b, c) __builtin_amdgcn_mfma_f32_16x16x32_bf16((a), (b), (c), 0, 0, 0)

static constexpr int BATCH = 4;
static constexpr int QLEN  = 4096;
static constexpr int KLEN  = 4096;
static constexpr int DDIM  = 64;
static constexpr int VDIM  = 64;
static constexpr int NCHUNK = 4;                 // split-K factor
static constexpr int CKEYS  = KLEN / NCHUNK;     // 1024 keys per chunk
static constexpr float SCALE = 0.125f;           // 1/sqrt(64)

__device__ __forceinline__ short f2bf(float x) {
    union { float f; uint32_t u; } v; v.f = x;
    uint32_t u = v.u;
    return (short)((u + 0x7fffu + ((u >> 16) & 1u)) >> 16);   // RNE
}
__device__ __forceinline__ bf16x8 neg8(bf16x8 x) {
#pragma unroll
    for (int i = 0; i < 8; ++i) x[i] ^= (short)0x8000;
    return x;
}

// Block-uniform dtype detect: bf16-packed u32 pairs vs float2 per element.
__device__ __forceinline__ bool detect_bf(const uint32_t* src, int tid, int nthreads, int* scnt) {
    if (tid == 0) *scnt = 0;
    __syncthreads();
    int local = 0;
    for (int i = tid; i < 1024; i += nthreads) {
        uint32_t e = (src[i] >> 7) & 0xFFu;
        local += (e >= 110u && e <= 135u) ? 1 : 0;
    }
    atomicAdd(scnt, local);
    __syncthreads();
    return *scnt > 512;
}

// ---------- preprocess: complex [N] elements -> bf16 r/i planes ----------
__global__ void conv_kernel(const void* __restrict__ src,
                            uint16_t* __restrict__ dr, uint16_t* __restrict__ di, int n) {
    __shared__ int scnt;
    const bool isbf = detect_bf((const uint32_t*)src, threadIdx.x, blockDim.x, &scnt);
    int i = blockIdx.x * blockDim.x + threadIdx.x;
    if (i >= n) return;
    if (isbf) {
        uint32_t w = ((const uint32_t*)src)[i];
        dr[i] = (uint16_t)(w & 0xffffu);
        di[i] = (uint16_t)(w >> 16);
    } else {
        float2 f = ((const float2*)src)[i];
        dr[i] = (uint16_t)f2bf(f.x);
        di[i] = (uint16_t)f2bf(f.y);
    }
}

// ---------- preprocess: V [b][k][v] -> VrT/ViT [b][v][k] bf16 ----------
__global__ void vtrans_kernel(const void* __restrict__ src,
                              uint16_t* __restrict__ vr, uint16_t* __restrict__ vi) {
    __shared__ int scnt;
    __shared__ uint16_t tr[32][33];
    __shared__ uint16_t ti[32][33];
    const int tx = threadIdx.x, ty = threadIdx.y;   // 32 x 8
    const bool isbf = detect_bf((const uint32_t*)src, ty * 32 + tx, 256, &scnt);
    const int b  = blockIdx.z;
    const int k0 = blockIdx.x * 32;
    const int v0 = blockIdx.y * 32;
#pragma unroll
    for (int yy = 0; yy < 4; ++yy) {
        int kl = ty + yy * 8;
        size_t idx = ((size_t)b * KLEN + (k0 + kl)) * VDIM + v0 + tx;
        uint16_t r, im;
        if (isbf) {
            uint32_t w = ((const uint32_t*)src)[idx];
            r = (uint16_t)(w & 0xffffu); im = (uint16_t)(w >> 16);
        } else {
            float2 f = ((const float2*)src)[idx];
            r = (uint16_t)f2bf(f.x); im = (uint16_t)f2bf(f.y);
        }
        tr[kl][tx] = r;
        ti[kl][tx] = im;
    }
    __syncthreads();
#pragma unroll
    for (int yy = 0; yy < 4; ++yy) {
        int vl = ty + yy * 8;
        size_t o = ((size_t)b * VDIM + (v0 + vl)) * KLEN + k0 + tx;
        vr[o] = tr[tx][vl];
        vi[o] = ti[tx][vl];
    }
}

// ---------- main: split-K flash complex attention, one wave per (16 q-rows, 1024 keys) ----------
__launch_bounds__(64)
__global__ void cattn_split(const uint16_t* __restrict__ Qr, const uint16_t* __restrict__ Qi,
                            const uint16_t* __restrict__ Kr, const uint16_t* __restrict__ Ki,
                            const uint16_t* __restrict__ VrT, const uint16_t* __restrict__ ViT,
                            float2* __restrict__ Ypart, float2* __restrict__ MLpart) {
    __shared__ __align__(16) uint16_t sPr[16][40];
    __shared__ __align__(16) uint16_t sPi[16][40];

    const int lane = threadIdx.x;
    const int r    = lane & 15;
    const int quad = lane >> 4;
    const int q0   = blockIdx.x * 16;
    const int c    = blockIdx.y;
    const int b    = blockIdx.z;

    const size_t qrow = ((size_t)b * QLEN + q0 + r) * DDIM + quad * 8;
    const bf16x8 aQr0 = *(const bf16x8*)(Qr + qrow);
    const bf16x8 aQr1 = *(const bf16x8*)(Qr + qrow + 32);
    const bf16x8 aQi0 = *(const bf16x8*)(Qi + qrow);
    const bf16x8 aQi1 = *(const bf16x8*)(Qi + qrow + 32);
    const bf16x8 aQn0 = neg8(aQi0);
    const bf16x8 aQn1 = neg8(aQi1);

    f32x4 Yr[4], Yi[4];
#pragma unroll
    for (int i = 0; i < 4; ++i) { Yr[i] = (f32x4){0.f,0.f,0.f,0.f}; Yi[i] = (f32x4){0.f,0.f,0.f,0.f}; }
    float m_run[4] = {0.f, 0.f, 0.f, 0.f};
    float l_run[4] = {0.f, 0.f, 0.f, 0.f};

    const uint16_t* Krb = Kr  + (size_t)b * KLEN * DDIM;
    const uint16_t* Kib = Ki  + (size_t)b * KLEN * DDIM;
    const uint16_t* Vrb = VrT + (size_t)b * VDIM * KLEN;
    const uint16_t* Vib = ViT + (size_t)b * VDIM * KLEN;

    const int kbeg = c * CKEYS;
    for (int kt = kbeg; kt < kbeg + CKEYS; kt += 32) {
        f32x4 Sr[2], Si[2];
#pragma unroll
        for (int sub = 0; sub < 2; ++sub) {
            size_t ko = (size_t)(kt + sub * 16 + r) * DDIM + quad * 8;
            bf16x8 kr0 = *(const bf16x8*)(Krb + ko);
            bf16x8 kr1 = *(const bf16x8*)(Krb + ko + 32);
            bf16x8 ki0 = *(const bf16x8*)(Kib + ko);
            bf16x8 ki1 = *(const bf16x8*)(Kib + ko + 32);
            f32x4 cc = (f32x4){0.f,0.f,0.f,0.f};
            cc = MFMA16(aQr0, kr0, cc);
            cc = MFMA16(aQr1, kr1, cc);
            cc = MFMA16(aQi0, ki0, cc);
            cc = MFMA16(aQi1, ki1, cc);
            Sr[sub] = cc;
            f32x4 dd = (f32x4){0.f,0.f,0.f,0.f};
            dd = MFMA16(aQr0, ki0, dd);
            dd = MFMA16(aQr1, ki1, dd);
            dd = MFMA16(aQn0, kr0, dd);
            dd = MFMA16(aQn1, kr1, dd);
            Si[sub] = dd;
        }

        float nrm[2][4], tmax[4];
#pragma unroll
        for (int g = 0; g < 4; ++g) {
            float sr0 = Sr[0][g] * SCALE, si0 = Si[0][g] * SCALE;
            float sr1 = Sr[1][g] * SCALE, si1 = Si[1][g] * SCALE;
            Sr[0][g] = sr0; Si[0][g] = si0; Sr[1][g] = sr1; Si[1][g] = si1;
            nrm[0][g] = sqrtf(sr0 * sr0 + si0 * si0);
            nrm[1][g] = sqrtf(sr1 * sr1 + si1 * si1);
            tmax[g] = fmaxf(nrm[0][g], nrm[1][g]);
        }
#pragma unroll
        for (int off = 1; off < 16; off <<= 1) {
#pragma unroll
            for (int g = 0; g < 4; ++g)
                tmax[g] = fmaxf(tmax[g], __shfl_xor(tmax[g], off));
        }

        float alpha[4], psum[4];
#pragma unroll
        for (int g = 0; g < 4; ++g) {
            float mn = fmaxf(m_run[g], tmax[g]);
            alpha[g] = __expf(m_run[g] - mn);
            m_run[g] = mn;
            float p0 = __expf(nrm[0][g] - mn);
            float p1 = __expf(nrm[1][g] - mn);
            psum[g] = p0 + p1;
            float w0 = p0 / (nrm[0][g] + 1e-9f);
            float w1 = p1 / (nrm[1][g] + 1e-9f);
            int row = quad * 4 + g;
            sPr[row][r]      = (uint16_t)f2bf(Sr[0][g] * w0);
            sPi[row][r]      = (uint16_t)f2bf(Si[0][g] * w0);
            sPr[row][r + 16] = (uint16_t)f2bf(Sr[1][g] * w1);
            sPi[row][r + 16] = (uint16_t)f2bf(Si[1][g] * w1);
        }
#pragma unroll
        for (int off = 1; off < 16; off <<= 1) {
#pragma unroll
            for (int g = 0; g < 4; ++g)
                psum[g] += __shfl_xor(psum[g], off);
        }
#pragma unroll
        for (int g = 0; g < 4; ++g) {
            l_run[g] = l_run[g] * alpha[g] + psum[g];
#pragma unroll
            for (int vs = 0; vs < 4; ++vs) { Yr[vs][g] *= alpha[g]; Yi[vs][g] *= alpha[g]; }
        }

        __syncthreads();
        bf16x8 aPr = *(const bf16x8*)&sPr[r][quad * 8];
        bf16x8 aPi = *(const bf16x8*)&sPi[r][quad * 8];
        bf16x8 aPn = neg8(aPi);
#pragma unroll
        for (int vs = 0; vs < 4; ++vs) {
            size_t vo = (size_t)(vs * 16 + r) * KLEN + kt + quad * 8;
            bf16x8 bvr = *(const bf16x8*)(Vrb + vo);
            bf16x8 bvi = *(const bf16x8*)(Vib + vo);
            Yr[vs] = MFMA16(aPr, bvr, Yr[vs]);
            Yr[vs] = MFMA16(aPn, bvi, Yr[vs]);
            Yi[vs] = MFMA16(aPr, bvi, Yi[vs]);
            Yi[vs] = MFMA16(aPi, bvr, Yi[vs]);
        }
        __syncthreads();
    }

    // ---- write un-normalized partials + (m,l) ----
    const size_t pbase = ((size_t)(c * BATCH + b) * QLEN);
#pragma unroll
    for (int g = 0; g < 4; ++g) {
        int q = q0 + quad * 4 + g;
#pragma unroll
        for (int vs = 0; vs < 4; ++vs) {
            int v = vs * 16 + r;
            Ypart[(pbase + q) * VDIM + v] = make_float2(Yr[vs][g], Yi[vs][g]);
        }
    }
    if (r == 0) {
#pragma unroll
        for (int g = 0; g < 4; ++g) {
            int q = q0 + quad * 4 + g;
            MLpart[pbase + q] = make_float2(m_run[g], l_run[g]);
        }
    }
}

// ---------- combine 4 split-K partials ----------
__launch_bounds__(64)
__global__ void combine_kernel(const float2* __restrict__ Ypart, const float2* __restrict__ MLpart,
                               float2* __restrict__ out) {
    const int v = threadIdx.x;
    const int q = blockIdx.x;
    const int b = blockIdx.y;

    float m[NCHUNK], l[NCHUNK];
    float M = 0.f;
#pragma unroll
    for (int c = 0; c < NCHUNK; ++c) {
        float2 ml = MLpart[((size_t)(c * BATCH + b) * QLEN) + q];
        m[c] = ml.x; l[c] = ml.y;
        M = fmaxf(M, m[c]);
    }
    float L = 0.f, yr = 0.f, yi = 0.f;
#pragma unroll
    for (int c = 0; c < NCHUNK; ++c) {
        float w = __expf(m[c] - M);
        L += w * l[c];
        float2 y = Ypart[(((size_t)(c * BATCH + b) * QLEN) + q) * VDIM + v];
        yr += w * y.x;
        yi += w * y.y;
    }
    float inv = 1.0f / L;
    out[((size_t)b * QLEN + q) * VDIM + v] = make_float2(yr * inv, yi * inv);
}

// ================== fallback (proven round-5 kernel, no workspace) ==================
__device__ __forceinline__ void load8(const void* base, size_t eidx, bool isbf,
                                      bf16x8& re, bf16x8& im) {
    if (isbf) {
        const uint32_t* p = (const uint32_t*)base + eidx;
        uint4 a = ((const uint4*)p)[0];
        uint4 b = ((const uint4*)p)[1];
        uint32_t x[8] = {a.x, a.y, a.z, a.w, b.x, b.y, b.z, b.w};
#pragma unroll
        for (int j = 0; j < 8; ++j) { re[j] = (short)(x[j] & 0xffffu); im[j] = (short)(x[j] >> 16); }
    } else {
        const float4* p = (const float4*)((const float*)base + 2 * eidx);
        float4 f0 = p[0], f1 = p[1], f2 = p[2], f3 = p[3];
        re[0] = f2bf(f0.x); im[0] = f2bf(f0.y); re[1] = f2bf(f0.z); im[1] = f2bf(f0.w);
        re[2] = f2bf(f1.x); im[2] = f2bf(f1.y); re[3] = f2bf(f1.z); im[3] = f2bf(f1.w);
        re[4] = f2bf(f2.x); im[4] = f2bf(f2.y); re[5] = f2bf(f2.z); im[5] = f2bf(f2.w);
        re[6] = f2bf(f3.x); im[6] = f2bf(f3.y); re[7] = f2bf(f3.z); im[7] = f2bf(f3.w);
    }
}
__device__ __forceinline__ void load8_strided(const void* base, size_t ebase, bool isbf,
                                              bf16x8& re, bf16x8& im) {
    if (isbf) {
        const uint32_t* p = (const uint32_t*)base;
#pragma unroll
        for (int j = 0; j < 8; ++j) {
            uint32_t x = p[ebase + (size_t)j * VDIM];
            re[j] = (short)(x & 0xffffu); im[j] = (short)(x >> 16);
        }
    } else {
        const float2* p = (const float2*)base;
#pragma unroll
        for (int j = 0; j < 8; ++j) {
            float2 f = p[ebase + (size_t)j * VDIM];
            re[j] = f2bf(f.x); im[j] = f2bf(f.y);
        }
    }
}

__launch_bounds__(64)
__global__ void cattn_kernel(const void* __restrict__ Qp, const void* __restrict__ Kp,
                             const void* __restrict__ Vp, float2* __restrict__ out) {
    __shared__ __align__(16) uint16_t sPr[16][40];
    __shared__ __align__(16) uint16_t sPi[16][40];
    const int lane = threadIdx.x;
    const int r    = lane & 15;
    const int quad = lane >> 4;
    const int b    = blockIdx.y;
    const int q0   = blockIdx.x * 16;
    const uint32_t* qu = (const uint32_t*)Qp;
    int cnt = 0;
#pragma unroll
    for (int i = 0; i < 16; ++i) {
        uint32_t e = (qu[lane * 16 + i] >> 7) & 0xFFu;
        cnt += (e >= 110u && e <= 135u) ? 1 : 0;
    }
#pragma unroll
    for (int off = 32; off > 0; off >>= 1) cnt += __shfl_xor(cnt, off);
    const bool isbf = cnt > 512;
    bf16x8 aQr0, aQr1, aQi0, aQi1;
    const size_t qrow = ((size_t)b * QLEN + q0 + r) * DDIM;
    load8(Qp, qrow + quad * 8, isbf, aQr0, aQi0);
    load8(Qp, qrow + 32 + quad * 8, isbf, aQr1, aQi1);
    const bf16x8 aQn0 = neg8(aQi0);
    const bf16x8 aQn1 = neg8(aQi1);
    f32x4 Yr[4], Yi[4];
#pragma unroll
    for (int i = 0; i < 4; ++i) { Yr[i] = (f32x4){0.f,0.f,0.f,0.f}; Yi[i] = (f32x4){0.f,0.f,0.f,0.f}; }
    float m_run[4] = {0.f, 0.f, 0.f, 0.f};
    float l_run[4] = {0.f, 0.f, 0.f, 0.f};
    const size_t kbase = (size_t)b * KLEN * DDIM;
    const size_t vbase = (size_t)b * KLEN * VDIM;
    for (int kt = 0; kt < KLEN; kt += 32) {
        f32x4 Sr[2], Si[2];
#pragma unroll
        for (int sub = 0; sub < 2; ++sub) {
            size_t krow = kbase + (size_t)(kt + sub * 16 + r) * DDIM;
            bf16x8 kr0, ki0, kr1, ki1;
            load8(Kp, krow + quad * 8, isbf, kr0, ki0);
            load8(Kp, krow + 32 + quad * 8, isbf, kr1, ki1);
            f32x4 c = (f32x4){0.f,0.f,0.f,0.f};
            c = MFMA16(aQr0, kr0, c); c = MFMA16(aQr1, kr1, c);
            c = MFMA16(aQi0, ki0, c); c = MFMA16(aQi1, ki1, c);
            Sr[sub] = c;
            f32x4 d = (f32x4){0.f,0.f,0.f,0.f};
            d = MFMA16(aQr0, ki0, d); d = MFMA16(aQr1, ki1, d);
            d = MFMA16(aQn0, kr0, d); d = MFMA16(aQn1, kr1, d);
            Si[sub] = d;
        }
        float nrm[2][4], tmax[4];
#pragma unroll
        for (int g = 0; g < 4; ++g) {
            float sr0 = Sr[0][g] * SCALE, si0 = Si[0][g] * SCALE;
            float sr1 = Sr[1][g] * SCALE, si1 = Si[1][g] * SCALE;
            Sr[0][g] = sr0; Si[0][g] = si0; Sr[1][g] = sr1; Si[1][g] = si1;
            nrm[0][g] = sqrtf(sr0 * sr0 + si0 * si0);
            nrm[1][g] = sqrtf(sr1 * sr1 + si1 * si1);
            tmax[g] = fmaxf(nrm[0][g], nrm[1][g]);
        }
#pragma unroll
        for (int off = 1; off < 16; off <<= 1) {
#pragma unroll
            for (int g = 0; g < 4; ++g)
                tmax[g] = fmaxf(tmax[g], __shfl_xor(tmax[g], off));
        }
        float alpha[4], psum[4];
#pragma unroll
        for (int g = 0; g < 4; ++g) {
            float mn = fmaxf(m_run[g], tmax[g]);
            alpha[g] = __expf(m_run[g] - mn);
            m_run[g] = mn;
            float p0 = __expf(nrm[0][g] - mn);
            float p1 = __expf(nrm[1][g] - mn);
            psum[g] = p0 + p1;
            float w0 = p0 / (nrm[0][g] + 1e-9f);
            float w1 = p1 / (nrm[1][g] + 1e-9f);
            int row = quad * 4 + g;
            sPr[row][r]      = (uint16_t)f2bf(Sr[0][g] * w0);
            sPi[row][r]      = (uint16_t)f2bf(Si[0][g] * w0);
            sPr[row][r + 16] = (uint16_t)f2bf(Sr[1][g] * w1);
            sPi[row][r + 16] = (uint16_t)f2bf(Si[1][g] * w1);
        }
#pragma unroll
        for (int off = 1; off < 16; off <<= 1) {
#pragma unroll
            for (int g = 0; g < 4; ++g)
                psum[g] += __shfl_xor(psum[g], off);
        }
#pragma unroll
        for (int g = 0; g < 4; ++g) {
            l_run[g] = l_run[g] * alpha[g] + psum[g];
#pragma unroll
            for (int vs = 0; vs < 4; ++vs) { Yr[vs][g] *= alpha[g]; Yi[vs][g] *= alpha[g]; }
        }
        __syncthreads();
        bf16x8 aPr = *(const bf16x8*)&sPr[r][quad * 8];
        bf16x8 aPi = *(const bf16x8*)&sPi[r][quad * 8];
        bf16x8 aPn = neg8(aPi);
#pragma unroll
        for (int vs = 0; vs < 4; ++vs) {
            size_t ebase = vbase + (size_t)(kt + quad * 8) * VDIM + vs * 16 + r;
            bf16x8 bvr, bvi;
            load8_strided(Vp, ebase, isbf, bvr, bvi);
            Yr[vs] = MFMA16(aPr, bvr, Yr[vs]);
            Yr[vs] = MFMA16(aPn, bvi, Yr[vs]);
            Yi[vs] = MFMA16(aPr, bvi, Yi[vs]);
            Yi[vs] = MFMA16(aPi, bvr, Yi[vs]);
        }
        __syncthreads();
    }
#pragma unroll
    for (int g = 0; g < 4; ++g) {
        float inv = 1.0f / l_run[g];
        int q = q0 + quad * 4 + g;
#pragma unroll
        for (int vs = 0; vs < 4; ++vs) {
            int v = vs * 16 + r;
            out[((size_t)b * QLEN + q) * VDIM + v] = make_float2(Yr[vs][g] * inv, Yi[vs][g] * inv);
        }
    }
}

extern "C" void kernel_launch(void* const* d_in, const int* in_sizes, int n_in,
                              void* d_out, int out_size, void* d_ws, size_t ws_size,
                              hipStream_t stream) {
    (void)in_sizes; (void)n_in; (void)out_size;
    const size_t PL = (size_t)BATCH * QLEN * DDIM;                 // 1,048,576 elems
    const size_t planes_bytes = 6 * PL * sizeof(uint16_t);         // 12,582,912
    const size_t ypart_elems  = (size_t)NCHUNK * BATCH * QLEN * VDIM;
    const size_t mlpart_elems = (size_t)NCHUNK * BATCH * QLEN;
    const size_t need = planes_bytes + ypart_elems * sizeof(float2) + mlpart_elems * sizeof(float2);

    if (ws_size >= need) {
        uint16_t* w  = (uint16_t*)d_ws;
        uint16_t* Qr = w;
        uint16_t* Qi = w + PL;
        uint16_t* Kr = w + 2 * PL;
        uint16_t* Ki = w + 3 * PL;
        uint16_t* Vr = w + 4 * PL;
        uint16_t* Vi = w + 5 * PL;
        float2* Ypart  = (float2*)((char*)d_ws + planes_bytes);
        float2* MLpart = Ypart + ypart_elems;

        const int n = (int)PL;
        conv_kernel<<<dim3((n + 255) / 256), dim3(256), 0, stream>>>(d_in[0], Qr, Qi, n);
        conv_kernel<<<dim3((n + 255) / 256), dim3(256), 0, stream>>>(d_in[1], Kr, Ki, n);
        vtrans_kernel<<<dim3(KLEN / 32, VDIM / 32, BATCH), dim3(32, 8), 0, stream>>>(d_in[2], Vr, Vi);

        cattn_split<<<dim3(QLEN / 16, NCHUNK, BATCH), dim3(64), 0, stream>>>(
            Qr, Qi, Kr, Ki, Vr, Vi, Ypart, MLpart);

        combine_kernel<<<dim3(QLEN, BATCH), dim3(64), 0, stream>>>(Ypart, MLpart, (float2*)d_out);
    } else {
        cattn_kernel<<<dim3(QLEN / 16, BATCH), dim3(64), 0, stream>>>(
            d_in[0], d_in[1], d_in[2], (float2*)d_out);
    }
}

// Round 7
// 338.901 us; speedup vs baseline: 2.1979x; 1.0780x over previous
//
#include <hip/hip_runtime.h>
#include <stdint.h>

typedef __attribute__((ext_vector_type(8))) short bf16x8;
typedef __attribute__((ext_vector_type(4))) float f32x4;

#define MFMA16(a, b, c) __builtin_amdgcn_mfma_f32_16x16x32_bf16((a), (b), (c), 0, 0, 0)

#if __has_builtin(__builtin_amdgcn_rcpf)
#define FRCP(x) __builtin_amdgcn_rcpf(x)
#else
#define FRCP(x) (1.0f / (x))
#endif
#if __has_builtin(__builtin_amdgcn_sqrtf)
#define FSQRT(x) __builtin_amdgcn_sqrtf(x)
#else
#define FSQRT(x) sqrtf(x)
#endif

static constexpr int BATCH = 4;
static constexpr int QLEN  = 4096;
static constexpr int KLEN  = 4096;
static constexpr int DDIM  = 64;
static constexpr int VDIM  = 64;
static constexpr int NCHUNK = 4;                 // split-K factor
static constexpr int CKEYS  = KLEN / NCHUNK;     // 1024 keys per chunk
static constexpr float SCALE = 0.125f;           // 1/sqrt(64), folded into Q at preprocess

__device__ __forceinline__ float bf2f(uint32_t h) {
    union { uint32_t u; float f; } v; v.u = h << 16; return v.f;
}
__device__ __forceinline__ short f2bf(float x) {
    union { float f; uint32_t u; } v; v.f = x;
    uint32_t u = v.u;
    return (short)((u + 0x7fffu + ((u >> 16) & 1u)) >> 16);   // RNE
}
__device__ __forceinline__ bf16x8 neg8(bf16x8 x) {
#pragma unroll
    for (int i = 0; i < 8; ++i) x[i] ^= (short)0x8000;
    return x;
}

// Block-uniform dtype detect: bf16-packed u32 pairs vs float2 per element.
__device__ __forceinline__ bool detect_bf(const uint32_t* src, int tid, int nthreads, int* scnt) {
    if (tid == 0) *scnt = 0;
    __syncthreads();
    int local = 0;
    for (int i = tid; i < 1024; i += nthreads) {
        uint32_t e = (src[i] >> 7) & 0xFFu;
        local += (e >= 110u && e <= 135u) ? 1 : 0;
    }
    atomicAdd(scnt, local);
    __syncthreads();
    return *scnt > 512;
}

// ---------- preprocess: Q (pre-scaled by 1/sqrt(D)) and K -> bf16 r/i planes ----------
__global__ void qk_conv(const void* __restrict__ qsrc, const void* __restrict__ ksrc,
                        uint16_t* __restrict__ Qr, uint16_t* __restrict__ Qi,
                        uint16_t* __restrict__ Kr, uint16_t* __restrict__ Ki, int n) {
    __shared__ int scnt;
    const bool isQ = (blockIdx.y == 0);
    const void* src = isQ ? qsrc : ksrc;
    const bool isbf = detect_bf((const uint32_t*)src, threadIdx.x, blockDim.x, &scnt);
    int i = blockIdx.x * blockDim.x + threadIdx.x;
    if (i >= n) return;
    float re, im;
    if (isbf) {
        uint32_t w = ((const uint32_t*)src)[i];
        re = bf2f(w & 0xffffu); im = bf2f(w >> 16);
    } else {
        float2 f = ((const float2*)src)[i];
        re = f.x; im = f.y;
    }
    if (isQ) {
        Qr[i] = (uint16_t)f2bf(re * SCALE);   // exact pow2 scale
        Qi[i] = (uint16_t)f2bf(im * SCALE);
    } else {
        Kr[i] = (uint16_t)f2bf(re);
        Ki[i] = (uint16_t)f2bf(im);
    }
}

// ---------- preprocess: V [b][k][v] -> VrT/ViT [b][v][k] bf16 ----------
__global__ void vtrans_kernel(const void* __restrict__ src,
                              uint16_t* __restrict__ vr, uint16_t* __restrict__ vi) {
    __shared__ int scnt;
    __shared__ uint16_t tr[32][33];
    __shared__ uint16_t ti[32][33];
    const int tx = threadIdx.x, ty = threadIdx.y;   // 32 x 8
    const bool isbf = detect_bf((const uint32_t*)src, ty * 32 + tx, 256, &scnt);
    const int b  = blockIdx.z;
    const int k0 = blockIdx.x * 32;
    const int v0 = blockIdx.y * 32;
#pragma unroll
    for (int yy = 0; yy < 4; ++yy) {
        int kl = ty + yy * 8;
        size_t idx = ((size_t)b * KLEN + (k0 + kl)) * VDIM + v0 + tx;
        uint16_t r, im;
        if (isbf) {
            uint32_t w = ((const uint32_t*)src)[idx];
            r = (uint16_t)(w & 0xffffu); im = (uint16_t)(w >> 16);
        } else {
            float2 f = ((const float2*)src)[idx];
            r = (uint16_t)f2bf(f.x); im = (uint16_t)f2bf(f.y);
        }
        tr[kl][tx] = r;
        ti[kl][tx] = im;
    }
    __syncthreads();
#pragma unroll
    for (int yy = 0; yy < 4; ++yy) {
        int vl = ty + yy * 8;
        size_t o = ((size_t)b * VDIM + (v0 + vl)) * KLEN + k0 + tx;
        vr[o] = tr[tx][vl];
        vi[o] = ti[tx][vl];
    }
}

// ---------- main: split-K flash complex attention ----------
// 256 threads = 4 INDEPENDENT waves, each with private LDS P-buffers -> NO barriers.
__launch_bounds__(256, 4)
__global__ void cattn_split(const uint16_t* __restrict__ Qr, const uint16_t* __restrict__ Qi,
                            const uint16_t* __restrict__ Kr, const uint16_t* __restrict__ Ki,
                            const uint16_t* __restrict__ VrT, const uint16_t* __restrict__ ViT,
                            float2* __restrict__ Ypart, float2* __restrict__ MLpart) {
    __shared__ __align__(16) uint16_t sPr[4][16][40];   // per-wave private
    __shared__ __align__(16) uint16_t sPi[4][16][40];

    const int wave = threadIdx.x >> 6;
    const int lane = threadIdx.x & 63;
    const int r    = lane & 15;
    const int quad = lane >> 4;
    const int q0   = blockIdx.x * 64 + wave * 16;
    const int c    = blockIdx.y;
    const int b    = blockIdx.z;

    uint16_t (*Pr)[40] = sPr[wave];
    uint16_t (*Pi)[40] = sPi[wave];

    const size_t qrow = ((size_t)b * QLEN + q0 + r) * DDIM + quad * 8;
    const bf16x8 aQr0 = *(const bf16x8*)(Qr + qrow);
    const bf16x8 aQr1 = *(const bf16x8*)(Qr + qrow + 32);
    const bf16x8 aQi0 = *(const bf16x8*)(Qi + qrow);
    const bf16x8 aQi1 = *(const bf16x8*)(Qi + qrow + 32);
    const bf16x8 aQn0 = neg8(aQi0);
    const bf16x8 aQn1 = neg8(aQi1);

    f32x4 Yr[4], Yi[4];
#pragma unroll
    for (int i = 0; i < 4; ++i) { Yr[i] = (f32x4){0.f,0.f,0.f,0.f}; Yi[i] = (f32x4){0.f,0.f,0.f,0.f}; }
    float m_run[4] = {0.f, 0.f, 0.f, 0.f};   // norms >= 0, so 0 is a safe -inf
    float l_run[4] = {0.f, 0.f, 0.f, 0.f};

    const uint16_t* Krb = Kr  + (size_t)b * KLEN * DDIM;
    const uint16_t* Kib = Ki  + (size_t)b * KLEN * DDIM;
    const uint16_t* Vrb = VrT + (size_t)b * VDIM * KLEN;
    const uint16_t* Vib = ViT + (size_t)b * VDIM * KLEN;

    const int kbeg = c * CKEYS;
    for (int kt = kbeg; kt < kbeg + CKEYS; kt += 32) {
        // ---- S = QK^T (pre-scaled), two 16-key subtiles ----
        f32x4 Sr[2], Si[2];
#pragma unroll
        for (int sub = 0; sub < 2; ++sub) {
            size_t ko = (size_t)(kt + sub * 16 + r) * DDIM + quad * 8;
            bf16x8 kr0 = *(const bf16x8*)(Krb + ko);
            bf16x8 kr1 = *(const bf16x8*)(Krb + ko + 32);
            bf16x8 ki0 = *(const bf16x8*)(Kib + ko);
            bf16x8 ki1 = *(const bf16x8*)(Kib + ko + 32);
            f32x4 cc = (f32x4){0.f,0.f,0.f,0.f};
            cc = MFMA16(aQr0, kr0, cc);
            cc = MFMA16(aQr1, kr1, cc);
            cc = MFMA16(aQi0, ki0, cc);
            cc = MFMA16(aQi1, ki1, cc);
            Sr[sub] = cc;
            f32x4 dd = (f32x4){0.f,0.f,0.f,0.f};
            dd = MFMA16(aQr0, ki0, dd);
            dd = MFMA16(aQr1, ki1, dd);
            dd = MFMA16(aQn0, kr0, dd);
            dd = MFMA16(aQn1, kr1, dd);
            Si[sub] = dd;
        }

        // ---- norms + row max ----
        float nrm[2][4], tmax[4];
#pragma unroll
        for (int g = 0; g < 4; ++g) {
            nrm[0][g] = FSQRT(Sr[0][g] * Sr[0][g] + Si[0][g] * Si[0][g]);
            nrm[1][g] = FSQRT(Sr[1][g] * Sr[1][g] + Si[1][g] * Si[1][g]);
            tmax[g] = fmaxf(nrm[0][g], nrm[1][g]);
        }
#pragma unroll
        for (int off = 1; off < 16; off <<= 1) {
#pragma unroll
            for (int g = 0; g < 4; ++g)
                tmax[g] = fmaxf(tmax[g], __shfl_xor(tmax[g], off));
        }

        // ---- online max update; rescale only when some row's max grew ----
        float mn[4];
        bool chg = false;
#pragma unroll
        for (int g = 0; g < 4; ++g) {
            mn[g] = fmaxf(m_run[g], tmax[g]);
            chg = chg || (mn[g] > m_run[g]);
        }
        if (__any(chg)) {
#pragma unroll
            for (int g = 0; g < 4; ++g) {
                float a = __expf(m_run[g] - mn[g]);
                m_run[g] = mn[g];
                l_run[g] *= a;
#pragma unroll
                for (int vs = 0; vs < 4; ++vs) { Yr[vs][g] *= a; Yi[vs][g] *= a; }
            }
        }

        // ---- P = S * exp(nrm-m)/(nrm+eps) -> private LDS (bf16) ----
        float psum[4];
#pragma unroll
        for (int g = 0; g < 4; ++g) {
            float p0 = __expf(nrm[0][g] - mn[g]);
            float p1 = __expf(nrm[1][g] - mn[g]);
            psum[g] = p0 + p1;
            float w0 = p0 * FRCP(nrm[0][g] + 1e-9f);
            float w1 = p1 * FRCP(nrm[1][g] + 1e-9f);
            int row = quad * 4 + g;
            Pr[row][r]      = (uint16_t)f2bf(Sr[0][g] * w0);
            Pi[row][r]      = (uint16_t)f2bf(Si[0][g] * w0);
            Pr[row][r + 16] = (uint16_t)f2bf(Sr[1][g] * w1);
            Pi[row][r + 16] = (uint16_t)f2bf(Si[1][g] * w1);
        }
#pragma unroll
        for (int off = 1; off < 16; off <<= 1) {
#pragma unroll
            for (int g = 0; g < 4; ++g)
                psum[g] += __shfl_xor(psum[g], off);
        }
#pragma unroll
        for (int g = 0; g < 4; ++g) l_run[g] += psum[g];

        // ---- P as A-fragment (same-wave LDS: ordered by lgkmcnt, no barrier) ----
        bf16x8 aPr = *(const bf16x8*)&Pr[r][quad * 8];
        bf16x8 aPi = *(const bf16x8*)&Pi[r][quad * 8];
        bf16x8 aPn = neg8(aPi);
#pragma unroll
        for (int vs = 0; vs < 4; ++vs) {
            size_t vo = (size_t)(vs * 16 + r) * KLEN + kt + quad * 8;
            bf16x8 bvr = *(const bf16x8*)(Vrb + vo);
            bf16x8 bvi = *(const bf16x8*)(Vib + vo);
            Yr[vs] = MFMA16(aPr, bvr, Yr[vs]);
            Yr[vs] = MFMA16(aPn, bvi, Yr[vs]);
            Yi[vs] = MFMA16(aPr, bvi, Yi[vs]);
            Yi[vs] = MFMA16(aPi, bvr, Yi[vs]);
        }
    }

    // ---- write un-normalized partials + (m,l) ----
    const size_t pbase = ((size_t)(c * BATCH + b) * QLEN);
#pragma unroll
    for (int g = 0; g < 4; ++g) {
        int q = q0 + quad * 4 + g;
#pragma unroll
        for (int vs = 0; vs < 4; ++vs) {
            int v = vs * 16 + r;
            Ypart[(pbase + q) * VDIM + v] = make_float2(Yr[vs][g], Yi[vs][g]);
        }
    }
    if (r == 0) {
#pragma unroll
        for (int g = 0; g < 4; ++g) {
            int q = q0 + quad * 4 + g;
            MLpart[pbase + q] = make_float2(m_run[g], l_run[g]);
        }
    }
}

// ---------- combine split-K partials ----------
__launch_bounds__(64)
__global__ void combine_kernel(const float2* __restrict__ Ypart, const float2* __restrict__ MLpart,
                               float2* __restrict__ out) {
    const int v = threadIdx.x;
    const int q = blockIdx.x;
    const int b = blockIdx.y;

    float m[NCHUNK], l[NCHUNK];
    float M = 0.f;
#pragma unroll
    for (int c = 0; c < NCHUNK; ++c) {
        float2 ml = MLpart[((size_t)(c * BATCH + b) * QLEN) + q];
        m[c] = ml.x; l[c] = ml.y;
        M = fmaxf(M, m[c]);
    }
    float L = 0.f, yr = 0.f, yi = 0.f;
#pragma unroll
    for (int c = 0; c < NCHUNK; ++c) {
        float w = __expf(m[c] - M);
        L += w * l[c];
        float2 y = Ypart[(((size_t)(c * BATCH + b) * QLEN) + q) * VDIM + v];
        yr += w * y.x;
        yi += w * y.y;
    }
    float inv = 1.0f / L;
    out[((size_t)b * QLEN + q) * VDIM + v] = make_float2(yr * inv, yi * inv);
}

// ================== fallback (proven round-5 kernel, no workspace) ==================
__device__ __forceinline__ void load8(const void* base, size_t eidx, bool isbf,
                                      bf16x8& re, bf16x8& im) {
    if (isbf) {
        const uint32_t* p = (const uint32_t*)base + eidx;
        uint4 a = ((const uint4*)p)[0];
        uint4 b = ((const uint4*)p)[1];
        uint32_t x[8] = {a.x, a.y, a.z, a.w, b.x, b.y, b.z, b.w};
#pragma unroll
        for (int j = 0; j < 8; ++j) { re[j] = (short)(x[j] & 0xffffu); im[j] = (short)(x[j] >> 16); }
    } else {
        const float4* p = (const float4*)((const float*)base + 2 * eidx);
        float4 f0 = p[0], f1 = p[1], f2 = p[2], f3 = p[3];
        re[0] = f2bf(f0.x); im[0] = f2bf(f0.y); re[1] = f2bf(f0.z); im[1] = f2bf(f0.w);
        re[2] = f2bf(f1.x); im[2] = f2bf(f1.y); re[3] = f2bf(f1.z); im[3] = f2bf(f1.w);
        re[4] = f2bf(f2.x); im[4] = f2bf(f2.y); re[5] = f2bf(f2.z); im[5] = f2bf(f2.w);
        re[6] = f2bf(f3.x); im[6] = f2bf(f3.y); re[7] = f2bf(f3.z); im[7] = f2bf(f3.w);
    }
}
__device__ __forceinline__ void load8_strided(const void* base, size_t ebase, bool isbf,
                                              bf16x8& re, bf16x8& im) {
    if (isbf) {
        const uint32_t* p = (const uint32_t*)base;
#pragma unroll
        for (int j = 0; j < 8; ++j) {
            uint32_t x = p[ebase + (size_t)j * VDIM];
            re[j] = (short)(x & 0xffffu); im[j] = (short)(x >> 16);
        }
    } else {
        const float2* p = (const float2*)base;
#pragma unroll
        for (int j = 0; j < 8; ++j) {
            float2 f = p[ebase + (size_t)j * VDIM];
            re[j] = f2bf(f.x); im[j] = f2bf(f.y);
        }
    }
}

__launch_bounds__(64)
__global__ void cattn_kernel(const void* __restrict__ Qp, const void* __restrict__ Kp,
                             const void* __restrict__ Vp, float2* __restrict__ out) {
    __shared__ __align__(16) uint16_t sPr[16][40];
    __shared__ __align__(16) uint16_t sPi[16][40];
    const int lane = threadIdx.x;
    const int r    = lane & 15;
    const int quad = lane >> 4;
    const int b    = blockIdx.y;
    const int q0   = blockIdx.x * 16;
    const uint32_t* qu = (const uint32_t*)Qp;
    int cnt = 0;
#pragma unroll
    for (int i = 0; i < 16; ++i) {
        uint32_t e = (qu[lane * 16 + i] >> 7) & 0xFFu;
        cnt += (e >= 110u && e <= 135u) ? 1 : 0;
    }
#pragma unroll
    for (int off = 32; off > 0; off >>= 1) cnt += __shfl_xor(cnt, off);
    const bool isbf = cnt > 512;
    bf16x8 aQr0, aQr1, aQi0, aQi1;
    const size_t qrow = ((size_t)b * QLEN + q0 + r) * DDIM;
    load8(Qp, qrow + quad * 8, isbf, aQr0, aQi0);
    load8(Qp, qrow + 32 + quad * 8, isbf, aQr1, aQi1);
    const bf16x8 aQn0 = neg8(aQi0);
    const bf16x8 aQn1 = neg8(aQi1);
    f32x4 Yr[4], Yi[4];
#pragma unroll
    for (int i = 0; i < 4; ++i) { Yr[i] = (f32x4){0.f,0.f,0.f,0.f}; Yi[i] = (f32x4){0.f,0.f,0.f,0.f}; }
    float m_run[4] = {0.f, 0.f, 0.f, 0.f};
    float l_run[4] = {0.f, 0.f, 0.f, 0.f};
    const size_t kbase = (size_t)b * KLEN * DDIM;
    const size_t vbase = (size_t)b * KLEN * VDIM;
    for (int kt = 0; kt < KLEN; kt += 32) {
        f32x4 Sr[2], Si[2];
#pragma unroll
        for (int sub = 0; sub < 2; ++sub) {
            size_t krow = kbase + (size_t)(kt + sub * 16 + r) * DDIM;
            bf16x8 kr0, ki0, kr1, ki1;
            load8(Kp, krow + quad * 8, isbf, kr0, ki0);
            load8(Kp, krow + 32 + quad * 8, isbf, kr1, ki1);
            f32x4 c = (f32x4){0.f,0.f,0.f,0.f};
            c = MFMA16(aQr0, kr0, c); c = MFMA16(aQr1, kr1, c);
            c = MFMA16(aQi0, ki0, c); c = MFMA16(aQi1, ki1, c);
            Sr[sub] = c;
            f32x4 d = (f32x4){0.f,0.f,0.f,0.f};
            d = MFMA16(aQr0, ki0, d); d = MFMA16(aQr1, ki1, d);
            d = MFMA16(aQn0, kr0, d); d = MFMA16(aQn1, kr1, d);
            Si[sub] = d;
        }
        float nrm[2][4], tmax[4];
#pragma unroll
        for (int g = 0; g < 4; ++g) {
            float sr0 = Sr[0][g] * 0.125f, si0 = Si[0][g] * 0.125f;
            float sr1 = Sr[1][g] * 0.125f, si1 = Si[1][g] * 0.125f;
            Sr[0][g] = sr0; Si[0][g] = si0; Sr[1][g] = sr1; Si[1][g] = si1;
            nrm[0][g] = sqrtf(sr0 * sr0 + si0 * si0);
            nrm[1][g] = sqrtf(sr1 * sr1 + si1 * si1);
            tmax[g] = fmaxf(nrm[0][g], nrm[1][g]);
        }
#pragma unroll
        for (int off = 1; off < 16; off <<= 1) {
#pragma unroll
            for (int g = 0; g < 4; ++g)
                tmax[g] = fmaxf(tmax[g], __shfl_xor(tmax[g], off));
        }
        float alpha[4], psum[4];
#pragma unroll
        for (int g = 0; g < 4; ++g) {
            float mn = fmaxf(m_run[g], tmax[g]);
            alpha[g] = __expf(m_run[g] - mn);
            m_run[g] = mn;
            float p0 = __expf(nrm[0][g] - mn);
            float p1 = __expf(nrm[1][g] - mn);
            psum[g] = p0 + p1;
            float w0 = p0 / (nrm[0][g] + 1e-9f);
            float w1 = p1 / (nrm[1][g] + 1e-9f);
            int row = quad * 4 + g;
            sPr[row][r]      = (uint16_t)f2bf(Sr[0][g] * w0);
            sPi[row][r]      = (uint16_t)f2bf(Si[0][g] * w0);
            sPr[row][r + 16] = (uint16_t)f2bf(Sr[1][g] * w1);
            sPi[row][r + 16] = (uint16_t)f2bf(Si[1][g] * w1);
        }
#pragma unroll
        for (int off = 1; off < 16; off <<= 1) {
#pragma unroll
            for (int g = 0; g < 4; ++g)
                psum[g] += __shfl_xor(psum[g], off);
        }
#pragma unroll
        for (int g = 0; g < 4; ++g) {
            l_run[g] = l_run[g] * alpha[g] + psum[g];
#pragma unroll
            for (int vs = 0; vs < 4; ++vs) { Yr[vs][g] *= alpha[g]; Yi[vs][g] *= alpha[g]; }
        }
        __syncthreads();
        bf16x8 aPr = *(const bf16x8*)&sPr[r][quad * 8];
        bf16x8 aPi = *(const bf16x8*)&sPi[r][quad * 8];
        bf16x8 aPn = neg8(aPi);
#pragma unroll
        for (int vs = 0; vs < 4; ++vs) {
            size_t ebase = vbase + (size_t)(kt + quad * 8) * VDIM + vs * 16 + r;
            bf16x8 bvr, bvi;
            load8_strided(Vp, ebase, isbf, bvr, bvi);
            Yr[vs] = MFMA16(aPr, bvr, Yr[vs]);
            Yr[vs] = MFMA16(aPn, bvi, Yr[vs]);
            Yi[vs] = MFMA16(aPr, bvi, Yi[vs]);
            Yi[vs] = MFMA16(aPi, bvr, Yi[vs]);
        }
        __syncthreads();
    }
#pragma unroll
    for (int g = 0; g < 4; ++g) {
        float inv = 1.0f / l_run[g];
        int q = q0 + quad * 4 + g;
#pragma unroll
        for (int vs = 0; vs < 4; ++vs) {
            int v = vs * 16 + r;
            out[((size_t)b * QLEN + q) * VDIM + v] = make_float2(Yr[vs][g] * inv, Yi[vs][g] * inv);
        }
    }
}

extern "C" void kernel_launch(void* const* d_in, const int* in_sizes, int n_in,
                              void* d_out, int out_size, void* d_ws, size_t ws_size,
                              hipStream_t stream) {
    (void)in_sizes; (void)n_in; (void)out_size;
    const size_t PL = (size_t)BATCH * QLEN * DDIM;                 // 1,048,576 elems
    const size_t planes_bytes = 6 * PL * sizeof(uint16_t);         // 12,582,912
    const size_t ypart_elems  = (size_t)NCHUNK * BATCH * QLEN * VDIM;
    const size_t mlpart_elems = (size_t)NCHUNK * BATCH * QLEN;
    const size_t need = planes_bytes + ypart_elems * sizeof(float2) + mlpart_elems * sizeof(float2);

    if (ws_size >= need) {
        uint16_t* w  = (uint16_t*)d_ws;
        uint16_t* Qr = w;
        uint16_t* Qi = w + PL;
        uint16_t* Kr = w + 2 * PL;
        uint16_t* Ki = w + 3 * PL;
        uint16_t* Vr = w + 4 * PL;
        uint16_t* Vi = w + 5 * PL;
        float2* Ypart  = (float2*)((char*)d_ws + planes_bytes);
        float2* MLpart = Ypart + ypart_elems;

        const int n = (int)PL;
        qk_conv<<<dim3((n + 255) / 256, 2), dim3(256), 0, stream>>>(
            d_in[0], d_in[1], Qr, Qi, Kr, Ki, n);
        vtrans_kernel<<<dim3(KLEN / 32, VDIM / 32, BATCH), dim3(32, 8), 0, stream>>>(d_in[2], Vr, Vi);

        cattn_split<<<dim3(QLEN / 64, NCHUNK, BATCH), dim3(256), 0, stream>>>(
            Qr, Qi, Kr, Ki, Vr, Vi, Ypart, MLpart);

        combine_kernel<<<dim3(QLEN, BATCH), dim3(64), 0, stream>>>(Ypart, MLpart, (float2*)d_out);
    } else {
        cattn_kernel<<<dim3(QLEN / 16, BATCH), dim3(64), 0, stream>>>(
            d_in[0], d_in[1], d_in[2], (float2*)d_out);
    }
}